// Round 5
// baseline (101389.258 us; speedup 1.0000x reference)
//
#include <hip/hip_runtime.h>
#include <stdint.h>
#include <math.h>

#define T 4096
#define NTAGS 6
#define START_TAG 3
#define STOP_TAG 4
#define NEGV -10000.0f

__device__ __forceinline__ float sigm_fast(float z) {
  return 1.f / (1.f + __expf(-z));
}
__device__ __forceinline__ float tanh_fast(float z) {
  return 1.f - 2.f / (1.f + __expf(2.f * z));   // exact at +/-inf saturation
}

typedef _Float16 half2v __attribute__((ext_vector_type(2)));
__device__ __forceinline__ float dot2acc(unsigned a, unsigned b, float c) {
  return __builtin_amdgcn_fdot2(__builtin_bit_cast(half2v, a),
                                __builtin_bit_cast(half2v, b), c, false);
}
__device__ __forceinline__ unsigned short f16b(float x) {
  _Float16 h = (_Float16)x;
  return __builtin_bit_cast(unsigned short, h);
}
__device__ __forceinline__ unsigned pack2(float a, float b) {
  return (unsigned)f16b(a) | ((unsigned)f16b(b) << 16);
}

// ---------------------------------------------------------------------------
// Ring access. Fast path: sc0 (L1-bypass, L2-coherent) — valid because the
// claim protocol puts all 16 WGs of a direction on ONE XCD (shared L2).
// Safety net (placement-independent): producer also stores sc1 (MALL), and
// the poll falls back to an agent-scope load every 256 iterations. Same
// 8B value both ways -> benign race; correctness never depends on placement.
// ---------------------------------------------------------------------------
__device__ __forceinline__ void ring_store(unsigned long long* p,
                                           unsigned long long v) {
  asm volatile("global_store_dwordx2 %0, %1, off sc0" :: "v"(p), "v"(v)
               : "memory");
  asm volatile("global_store_dwordx2 %0, %1, off sc1" :: "v"(p), "v"(v)
               : "memory");
}
__device__ __forceinline__ unsigned long long ring_poll(
    unsigned long long* p, unsigned exp) {
  unsigned long long v;
  int it = 0;
  for (;;) {
    if (((++it) & 255) == 0) {
      v = __hip_atomic_load(p, __ATOMIC_RELAXED, __HIP_MEMORY_SCOPE_AGENT);
    } else {
      asm volatile("global_load_dwordx2 %0, %1, off sc0\n\ts_waitcnt vmcnt(0)"
                   : "=v"(v) : "v"(p) : "memory");
    }
    if ((unsigned)(v >> 32) == exp) break;
  }
  return v;
}

// ---------------------------------------------------------------------------
// K0: transpose w_ih (both dirs) into wT[k][col], col = d*1024+g (gate-major);
// combined bias; zero the k2 claim area (1 KB).
// ---------------------------------------------------------------------------
__global__ __launch_bounds__(256) void k0_prep(
    const float* __restrict__ wf, const float* __restrict__ wb,
    const float* __restrict__ bif, const float* __restrict__ bhf,
    const float* __restrict__ bib, const float* __restrict__ bhb,
    float* __restrict__ wT, float* __restrict__ bias2, int* claim) {
  int idx = blockIdx.x * 256 + threadIdx.x;   // 0 .. 524287
  int k = idx >> 11, col = idx & 2047;
  int d = col >> 10, g = col & 1023;
  const float* w = d ? wb : wf;
  wT[idx] = w[g * 256 + k];                   // wT[k*2048 + col]
  if (idx < 2048) bias2[idx] = d ? (bib[g] + bhb[g]) : (bif[g] + bhf[g]);
  if (blockIdx.x == 0 && threadIdx.x < 256) claim[threadIdx.x] = 0;
}

// ---------------------------------------------------------------------------
// K1: zpre[d][t][g] = emb[sent[t]] . w_ih[d][g] + b_ih + b_hh   (gate-major)
// ---------------------------------------------------------------------------
__global__ __launch_bounds__(256) void k1_zpre(
    const int* __restrict__ sent, const float* __restrict__ emb,
    const float* __restrict__ wT, const float* __restrict__ bias2,
    float* __restrict__ zpre) {
  int tb = blockIdx.x, cb = blockIdx.y;
  int tid = threadIdx.x;
  int col = cb * 256 + tid;
  int d = col >> 10, g = col & 1023;
  __shared__ float xs[32 * 256];
  int t0 = tb * 32;
  for (int r = 0; r < 32; r++) {
    int s = sent[t0 + r];                       // uniform -> scalar broadcast
    xs[r * 256 + tid] = emb[(size_t)s * 256 + tid];
  }
  __syncthreads();
  float acc[32];
#pragma unroll
  for (int r = 0; r < 32; r++) acc[r] = 0.f;
  const float4* xs4 = (const float4*)xs;
  for (int kq = 0; kq < 64; kq++) {
    float w0 = wT[(4 * kq + 0) * 2048 + col];
    float w1 = wT[(4 * kq + 1) * 2048 + col];
    float w2 = wT[(4 * kq + 2) * 2048 + col];
    float w3 = wT[(4 * kq + 3) * 2048 + col];
#pragma unroll
    for (int r = 0; r < 32; r++) {
      float4 x4 = xs4[r * 64 + kq];             // uniform address -> broadcast
      acc[r] += w0 * x4.x + w1 * x4.y + w2 * x4.z + w3 * x4.w;
    }
  }
  float bb = bias2[col];
  for (int r = 0; r < 32; r++)
    zpre[((size_t)d * T + (t0 + r)) * 1024 + g] = acc[r] + bb;
}

// ---------------------------------------------------------------------------
// K2 v8: v4's proven body (LDS f16 weights, k-split waves, 2 barriers/step,
// 16 updater threads, identical FP order) + XCD-local team placement so the
// ring lives in ONE XCD's L2 (sc0) instead of MALL.
// Claim: 256 WGs; per-XCD slot counter; slots 16k..16k+15 form a team; the
// 16th member claims a direction (global counter). >=8 complete teams exist
// for ANY dispatch distribution (pigeonhole, 256 > 8*15+2*16), so both
// directions are always claimed. Losers exit via mailbox code or the
// done0&&done1 escape (s_sleep backoff).
// ---------------------------------------------------------------------------
__global__ __launch_bounds__(256) void k2_lstm(
    const float* __restrict__ zpre,
    const float* __restrict__ whf, const float* __restrict__ whb,
    const float* __restrict__ h0, const float* __restrict__ c0,
    float* h_all, unsigned long long* ring, int* claim) {
  int tid = threadIdx.x;
  int q = tid >> 6, lane = tid & 63;

  // ---- XCD-local team claim ----
  __shared__ int s_role;
  if (tid == 0) {
    int xcd;
    asm volatile("s_getreg_b32 %0, hwreg(HW_REG_XCC_ID)" : "=s"(xcd));
    xcd &= 7;
    int slot = __hip_atomic_fetch_add(&claim[xcd], 1, __ATOMIC_RELAXED,
                                      __HIP_MEMORY_SCOPE_AGENT);
    int teamid = slot >> 4, member = slot & 15;
    int* mb = &claim[16 + xcd * 16 + teamid];
    int code = 0;
    if (member == 15) {                    // team complete: claim a direction
      int g = __hip_atomic_fetch_add(&claim[8], 1, __ATOMIC_RELAXED,
                                     __HIP_MEMORY_SCOPE_AGENT);
      code = (g < 2) ? (g + 1) : 3;
      __hip_atomic_store(mb, code, __ATOMIC_RELEASE,
                         __HIP_MEMORY_SCOPE_AGENT);
    }
    for (;;) {
      code = __hip_atomic_load(mb, __ATOMIC_ACQUIRE, __HIP_MEMORY_SCOPE_AGENT);
      if (code) break;
      int d0 = __hip_atomic_load(&claim[9], __ATOMIC_RELAXED,
                                 __HIP_MEMORY_SCOPE_AGENT);
      int d1 = __hip_atomic_load(&claim[10], __ATOMIC_RELAXED,
                                 __HIP_MEMORY_SCOPE_AGENT);
      if (d0 && d1) { code = 3; break; }   // incomplete team: exit when done
      __builtin_amdgcn_s_sleep(64);
    }
    s_role = (code == 3) ? -1 : ((code - 1) * 16 + member);
  }
  __syncthreads();
  int role = s_role;
  if (role < 0) return;
  int d = role >> 4, sub = role & 15;
  const float* w_hh = d ? whb : whf;

  __shared__ uint4 wl4[32 * 64];                    // 32 KB f16 weights
  __shared__ __align__(16) unsigned hq[4][32];      // per-wave h2 slices
  __shared__ float z_part[4][64];                   // per-wave partial z

  // ---- stage weights once (v4 layout) ----
  {
    unsigned short* wlh = (unsigned short*)wl4;
    for (int idx = tid; idx < 64 * 256; idx += 256) {
      int r = idx >> 8, k = idx & 255;
      int gate = r >> 4, cell = r & 15;
      float wv = w_hh[(size_t)(gate * 256 + sub * 16 + cell) * 256 + k];
      int sq = k >> 6, sm = (k >> 3) & 7, sj = k & 7;
      wlh[((sq * 8 + sm) * 64 + r) * 8 + sj] = f16b(wv);
    }
  }
  // ---- h0 into wave slices ----
  if (lane < 32) {
    float f0 = h0[d * 256 + q * 64 + 2 * lane];
    float f1 = h0[d * 256 + q * 64 + 2 * lane + 1];
    hq[q][lane] = pack2(f0, f1);
  }
  float c = 0.f;
  if (tid < 16) c = c0[d * 256 + sub * 16 + tid];

  const float* zp_d = zpre + (size_t)d * T * 1024;
  float* h_d = h_all + (size_t)d * T * 256;
  unsigned long long* rg = ring + (size_t)d * 2 * 128;

  // zpre for s=0, held by the 16 updater threads (4 gates each)
  float zv4[4] = {0.f, 0.f, 0.f, 0.f};
  if (tid < 16) {
    int t0 = d ? (T - 1) : 0;
#pragma unroll
    for (int g = 0; g < 4; g++)
      zv4[g] = zp_d[(size_t)t0 * 1024 + g * 256 + sub * 16 + tid];
  }
  __syncthreads();                                  // staging + h0 visible

  for (int s = 0; s < T; s++) {
    int t = d ? (T - 1 - s) : s;

    if (s > 0) {
      if (lane < 32) {
        unsigned long long v =
            ring_poll(&rg[((s - 1) & 1) * 128 + q * 32 + lane], (unsigned)s);
        hq[q][lane] = (unsigned)v;                  // wave-private slice
      }
      __builtin_amdgcn_wave_barrier();              // order hq write vs reads
    }

    // prefetch next-step zpre AFTER the poll: its latency hides under
    // dot + barriers + update, and the poll's vmcnt(0) no longer eats it.
    float zn4[4] = {0.f, 0.f, 0.f, 0.f};
    if (tid < 16 && s + 1 < T) {
      int tn = d ? (t - 1) : (t + 1);
#pragma unroll
      for (int g = 0; g < 4; g++)
        zn4[g] = zp_d[(size_t)tn * 1024 + g * 256 + sub * 16 + tid];
    }

    const uint4* hv = (const uint4*)hq[q];
    float acc = 0.f;
#pragma unroll
    for (int m = 0; m < 8; m++) {
      uint4 wv4 = wl4[(q * 8 + m) * 64 + lane];     // contiguous b128
      uint4 hv4 = hv[m];                            // wave-uniform broadcast
      acc = dot2acc(wv4.x, hv4.x, acc);
      acc = dot2acc(wv4.y, hv4.y, acc);
      acc = dot2acc(wv4.z, hv4.z, acc);
      acc = dot2acc(wv4.w, hv4.w, acc);
    }
    z_part[q][lane] = acc;
    __syncthreads();                                // (1) partials ready

    if (tid < 16) {
      float a[4];
#pragma unroll
      for (int g = 0; g < 4; g++) {
        int r = g * 16 + tid;
        float z = z_part[0][r] + z_part[1][r] + z_part[2][r] + z_part[3][r]
                + zv4[g];
        a[g] = (g == 2) ? tanh_fast(z) : sigm_fast(z);
      }
      c = a[1] * c + a[0] * a[2];
      float hvl = a[3] * tanh_fast(c);
      h_d[(size_t)t * 256 + sub * 16 + tid] = hvl;  // fp32 history for k3
      float hn = __shfl_down(hvl, 1);
      if ((tid & 1) == 0) {                         // pack 2 h per tagged entry
        unsigned h2 = pack2(0.f, 0.f);
        h2 = (unsigned)f16b(hvl) | ((unsigned)f16b(hn) << 16);
        ring_store(&rg[(s & 1) * 128 + sub * 8 + (tid >> 1)],
                   ((unsigned long long)(unsigned)(s + 1) << 32) | h2);
      }
#pragma unroll
      for (int g = 0; g < 4; g++) zv4[g] = zn4[g];
    }
    __syncthreads();                                // (2) z_part safe to reuse
  }

  if (tid == 0)
    __hip_atomic_store(&claim[9 + d], 1, __ATOMIC_RELEASE,
                       __HIP_MEMORY_SCOPE_AGENT);
}

// ---------------------------------------------------------------------------
// K3: feats[t][tag] = [hf[t]; hb[t]] . W_out[tag] + b_out[tag]
// ---------------------------------------------------------------------------
__global__ __launch_bounds__(64) void k3_feats(
    const float* __restrict__ h_all, const float* __restrict__ Wout,
    const float* __restrict__ bout, float* __restrict__ feats) {
  int t = blockIdx.x;
  int j = threadIdx.x;
  const float* hf = h_all + (size_t)t * 256;
  const float* hb = h_all + (size_t)T * 256 + (size_t)t * 256;
  float s[6];
#pragma unroll
  for (int g = 0; g < 6; g++) s[g] = 0.f;
#pragma unroll
  for (int m = 0; m < 4; m++) {
    float a = hf[j + 64 * m];
#pragma unroll
    for (int g = 0; g < 6; g++) s[g] += a * Wout[g * 512 + j + 64 * m];
  }
#pragma unroll
  for (int m = 0; m < 4; m++) {
    float b = hb[j + 64 * m];
#pragma unroll
    for (int g = 0; g < 6; g++) s[g] += b * Wout[g * 512 + 256 + j + 64 * m];
  }
#pragma unroll
  for (int g = 0; g < 6; g++) {
#pragma unroll
    for (int off = 32; off >= 1; off >>= 1) s[g] += __shfl_xor(s[g], off);
  }
  if (j < 6) feats[(size_t)t * 6 + j] = s[j] + bout[j];
}

// ---------------------------------------------------------------------------
// K4: Viterbi forward (serial, first-max argmax like jnp.argmax) + parallel
// backtrace via 6-entry map-composition suffix scan. Single wave.
// ---------------------------------------------------------------------------
__global__ __launch_bounds__(64) void k4_viterbi(
    const float* __restrict__ feats, const float* __restrict__ trans,
    float* __restrict__ out) {
  __shared__ unsigned char bp_lds[T * 8];
  __shared__ float fbuf[2][64 * 6];
  int lane = threadIdx.x;

  float tr[6];
#pragma unroll
  for (int f = 0; f < 6; f++) tr[f] = (lane < 6) ? trans[lane * 6 + f] : 0.f;
  float fv = (lane == START_TAG) ? 0.f : NEGV;

  for (int idx = lane; idx < 384; idx += 64) fbuf[0][idx] = feats[idx];

  for (int cch = 0; cch < 64; cch++) {
    float pf[6];
    if (cch + 1 < 64) {
#pragma unroll
      for (int m = 0; m < 6; m++)
        pf[m] = feats[(cch + 1) * 384 + lane + 64 * m];   // prefetch in regs
    }
    const float* fb = fbuf[cch & 1];
    for (int j = 0; j < 64; j++) {
      int t = cch * 64 + j;
      float best = -3.4e38f;
      int bi = 0;
#pragma unroll
      for (int f = 0; f < 6; f++) {
        float v = __shfl(fv, f) + tr[f];     // trans[to][from] + fv[from]
        if (v > best) { best = v; bi = f; }  // strict > => first max index
      }
      float nfv = best + fb[j * 6 + (lane < 6 ? lane : 0)];
      if (lane < 6) {
        fv = nfv;
        bp_lds[t * 8 + lane] = (unsigned char)bi;
      }
    }
    if (cch + 1 < 64) {
#pragma unroll
      for (int m = 0; m < 6; m++)
        fbuf[(cch + 1) & 1][lane + 64 * m] = pf[m];
    }
  }

  float term = (lane < 6) ? (fv + trans[STOP_TAG * 6 + lane]) : -3.4e38f;
  float bestv = -3.4e38f;
  int bestt = 0;
#pragma unroll
  for (int f = 0; f < 6; f++) {
    float v = __shfl(term, f);
    if (v > bestv) { bestv = v; bestt = f; }
  }
  if (lane == 0) out[0] = bestv;

  // backtrace: path[t] = S_t(best), S_t = M_{t+1} o ... o M_{T-1}
  unsigned int ident = 0;
#pragma unroll
  for (int i = 0; i < 6; i++) ident |= (unsigned)i << (3 * i);

  unsigned int p = ident;                 // P_L = M_{64L} o ... o M_{64L+63}
  int base = lane * 64;
  for (int j2 = 0; j2 < 64; j2++) {
    const unsigned int* bw = (const unsigned int*)&bp_lds[(base + j2) * 8];
    unsigned int lo = bw[0], hi = bw[1];
    unsigned int mw = (lo & 7) | (((lo >> 8) & 7) << 3) | (((lo >> 16) & 7) << 6)
                    | (((lo >> 24) & 7) << 9) | ((hi & 7) << 12)
                    | (((hi >> 8) & 7) << 15);
    unsigned int np = 0;
#pragma unroll
    for (int i = 0; i < 6; i++) {
      unsigned int b = (mw >> (3 * i)) & 7;
      np |= ((p >> (3 * b)) & 7) << (3 * i);   // p := p o M_t
    }
    p = np;
  }
  unsigned int suf = p;   // suffix scan: suf_L = P_L o ... o P_63
#pragma unroll
  for (int off = 1; off < 64; off <<= 1) {
    unsigned int other = __shfl_down(suf, off);
    if (lane + off < 64) {
      unsigned int ns = 0;
#pragma unroll
      for (int i = 0; i < 6; i++) {
        unsigned int b = (other >> (3 * i)) & 7;
        ns |= ((suf >> (3 * b)) & 7) << (3 * i);   // suf := suf o other
      }
      suf = ns;
    }
  }
  unsigned int tail = __shfl_down(suf, 1);     // Suf_{L+1}
  if (lane == 63) tail = ident;
  unsigned int cur = tail;                     // = S_{64L+63}
  for (int j2 = 63; j2 >= 0; j2--) {
    int t = base + j2;
    out[1 + t] = (float)((cur >> (3 * bestt)) & 7);
    const unsigned int* bw = (const unsigned int*)&bp_lds[t * 8];
    unsigned int lo = bw[0], hi = bw[1];
    unsigned int mw = (lo & 7) | (((lo >> 8) & 7) << 3) | (((lo >> 16) & 7) << 6)
                    | (((lo >> 24) & 7) << 9) | ((hi & 7) << 12)
                    | (((hi >> 8) & 7) << 15);
    unsigned int nc = 0;
#pragma unroll
    for (int i = 0; i < 6; i++) {
      unsigned int b = (cur >> (3 * i)) & 7;
      nc |= ((mw >> (3 * b)) & 7) << (3 * i);  // cur := M_t o cur
    }
    cur = nc;
  }
}

// ---------------------------------------------------------------------------
extern "C" void kernel_launch(void* const* d_in, const int* in_sizes, int n_in,
                              void* d_out, int out_size, void* d_ws, size_t ws_size,
                              hipStream_t stream) {
  const int*   sent  = (const int*)d_in[0];
  const float* emb   = (const float*)d_in[1];
  const float* wihf  = (const float*)d_in[2];
  const float* whhf  = (const float*)d_in[3];
  const float* bihf  = (const float*)d_in[4];
  const float* bhhf  = (const float*)d_in[5];
  const float* wihb  = (const float*)d_in[6];
  const float* whhb  = (const float*)d_in[7];
  const float* bihb  = (const float*)d_in[8];
  const float* bhhb  = (const float*)d_in[9];
  const float* Wout  = (const float*)d_in[10];
  const float* bout  = (const float*)d_in[11];
  const float* trans = (const float*)d_in[12];
  const float* h0    = (const float*)d_in[13];
  const float* c0    = (const float*)d_in[14];
  float* out = (float*)d_out;

  char* ws = (char*)d_ws;
  float*              zpre  = (float*)(ws + 0);          // 32 MiB
  float*              h_all = (float*)(ws + 33554432);   //  8 MiB
  float*              wT    = (float*)(ws + 41943040);   //  2 MiB
  float*              bias2 = (float*)(ws + 44040192);   //  8 KiB
  float*              feats = (float*)(ws + 44048384);   // 96 KiB
  unsigned long long* ring  = (unsigned long long*)(ws + 44146688); // 4 KiB
  int*                claim = (int*)(ws + 44150784);     //  1 KiB

  k0_prep<<<2048, 256, 0, stream>>>(wihf, wihb, bihf, bhhf, bihb, bhhb, wT,
                                    bias2, claim);
  dim3 g1(128, 8);
  k1_zpre<<<g1, 256, 0, stream>>>(sent, emb, wT, bias2, zpre);
  k2_lstm<<<256, 256, 0, stream>>>(zpre, whhf, whhb, h0, c0, h_all, ring, claim);
  k3_feats<<<4096, 64, 0, stream>>>(h_all, Wout, bout, feats);
  k4_viterbi<<<1, 64, 0, stream>>>(feats, trans, out);
}

// Round 6
// 6288.099 us; speedup vs baseline: 16.1240x; 16.1240x over previous
//
#include <hip/hip_runtime.h>
#include <stdint.h>
#include <math.h>

#define T 4096
#define NTAGS 6
#define START_TAG 3
#define STOP_TAG 4
#define NEGV -10000.0f

__device__ __forceinline__ float sigm_fast(float z) {
  return 1.f / (1.f + __expf(-z));
}
__device__ __forceinline__ float tanh_fast(float z) {
  return 1.f - 2.f / (1.f + __expf(2.f * z));   // exact at +/-inf saturation
}

typedef _Float16 half2v __attribute__((ext_vector_type(2)));
__device__ __forceinline__ float dot2acc(unsigned a, unsigned b, float c) {
  return __builtin_amdgcn_fdot2(__builtin_bit_cast(half2v, a),
                                __builtin_bit_cast(half2v, b), c, false);
}
__device__ __forceinline__ unsigned short f16b(float x) {
  _Float16 h = (_Float16)x;
  return __builtin_bit_cast(unsigned short, h);
}

// LDS-only barrier: orders DS ops across the WG WITHOUT the vmcnt(0) drain
// __syncthreads() emits. The outstanding agent-scope ring store and zpre
// prefetch keep draining in the background (their acks overlap the next
// step's poll). "memory" clobber + sched_barrier(0) pin ordering (rule #18).
__device__ __forceinline__ void lds_barrier() {
  __builtin_amdgcn_sched_barrier(0);
  asm volatile("s_waitcnt lgkmcnt(0)" ::: "memory");
  __builtin_amdgcn_s_barrier();
  __builtin_amdgcn_sched_barrier(0);
}

// 2-deep rotated poll: two loads in flight, check the older (compiler waits
// vmcnt(1), leaving the younger outstanding) -> mailbox sampled every ~RT/2
// instead of every RT.
__device__ __forceinline__ unsigned long long poll2(
    unsigned long long* addr, unsigned exp) {
  unsigned long long a = __hip_atomic_load(addr, __ATOMIC_RELAXED,
                                           __HIP_MEMORY_SCOPE_AGENT);
  unsigned long long b = __hip_atomic_load(addr, __ATOMIC_RELAXED,
                                           __HIP_MEMORY_SCOPE_AGENT);
  for (;;) {
    if ((unsigned)(a >> 32) == exp) return a;
    a = b;
    b = __hip_atomic_load(addr, __ATOMIC_RELAXED, __HIP_MEMORY_SCOPE_AGENT);
  }
}

// ---------------------------------------------------------------------------
// K0: transpose w_ih (both dirs) into wT[k][col], col = d*1024+g; combined bias
// ---------------------------------------------------------------------------
__global__ __launch_bounds__(256) void k0_prep(
    const float* __restrict__ wf, const float* __restrict__ wb,
    const float* __restrict__ bif, const float* __restrict__ bhf,
    const float* __restrict__ bib, const float* __restrict__ bhb,
    float* __restrict__ wT, float* __restrict__ bias2) {
  int idx = blockIdx.x * 256 + threadIdx.x;   // 0 .. 524287
  int k = idx >> 11, col = idx & 2047;
  int d = col >> 10, g = col & 1023;
  const float* w = d ? wb : wf;
  wT[idx] = w[g * 256 + k];                   // wT[k*2048 + col]
  if (idx < 2048) bias2[idx] = d ? (bib[g] + bhb[g]) : (bif[g] + bhf[g]);
}

// ---------------------------------------------------------------------------
// K1: zpre[d][t][g] = emb[sent[t]] . w_ih[d][g] + b_ih + b_hh
// ---------------------------------------------------------------------------
__global__ __launch_bounds__(256) void k1_zpre(
    const int* __restrict__ sent, const float* __restrict__ emb,
    const float* __restrict__ wT, const float* __restrict__ bias2,
    float* __restrict__ zpre) {
  int tb = blockIdx.x, cb = blockIdx.y;
  int tid = threadIdx.x;
  int col = cb * 256 + tid;
  int d = col >> 10, g = col & 1023;
  __shared__ float xs[32 * 256];
  int t0 = tb * 32;
  for (int r = 0; r < 32; r++) {
    int s = sent[t0 + r];                       // uniform -> scalar broadcast
    xs[r * 256 + tid] = emb[(size_t)s * 256 + tid];
  }
  __syncthreads();
  float acc[32];
#pragma unroll
  for (int r = 0; r < 32; r++) acc[r] = 0.f;
  const float4* xs4 = (const float4*)xs;
  for (int kq = 0; kq < 64; kq++) {
    float w0 = wT[(4 * kq + 0) * 2048 + col];
    float w1 = wT[(4 * kq + 1) * 2048 + col];
    float w2 = wT[(4 * kq + 2) * 2048 + col];
    float w3 = wT[(4 * kq + 3) * 2048 + col];
#pragma unroll
    for (int r = 0; r < 32; r++) {
      float4 x4 = xs4[r * 64 + kq];             // uniform address -> broadcast
      acc[r] += w0 * x4.x + w1 * x4.y + w2 * x4.z + w3 * x4.w;
    }
  }
  float bb = bias2[col];
  for (int r = 0; r < 32; r++)
    zpre[((size_t)d * T + (t0 + r)) * 1024 + g] = acc[r] + bb;
}

// ---------------------------------------------------------------------------
// K2 v9: v4's proven body (LDS f16 weights, k-split waves, 16 updater
// threads, identical FP order, identical ring protocol) with two surgical
// changes: (a) in-loop barriers are raw s_barrier + lgkmcnt(0) only -- the
// agent-scope ring store's MALL ack no longer serializes into the step;
// (b) 2-deep rotated poll halves mailbox sampling period.
// ---------------------------------------------------------------------------
__global__ __launch_bounds__(256) void k2_lstm(
    const float* __restrict__ zpre,
    const float* __restrict__ whf, const float* __restrict__ whb,
    const float* __restrict__ h0, const float* __restrict__ c0,
    float* h_all, unsigned long long* ring) {
  int w = blockIdx.x;
  int d = w >> 4, sub = w & 15;
  const float* w_hh = d ? whb : whf;
  int tid = threadIdx.x;
  int q = tid >> 6, lane = tid & 63;

  __shared__ uint4 wl4[32 * 64];                    // 32 KB f16 weights
  __shared__ __align__(16) unsigned hq[4][32];      // per-wave h2 slices
  __shared__ float z_part[4][64];                   // per-wave partial z

  // ---- stage weights once: half index ((q*8+m)*64 + r)*8 + j, k=64q+8m+j ---
  {
    unsigned short* wlh = (unsigned short*)wl4;
    for (int idx = tid; idx < 64 * 256; idx += 256) {
      int r = idx >> 8, k = idx & 255;
      int gate = r >> 4, cell = r & 15;
      float wv = w_hh[(size_t)(gate * 256 + sub * 16 + cell) * 256 + k];
      int sq = k >> 6, sm = (k >> 3) & 7, sj = k & 7;
      wlh[((sq * 8 + sm) * 64 + r) * 8 + sj] = f16b(wv);
    }
  }
  // ---- h0 into wave slices ----
  if (lane < 32) {
    float f0 = h0[d * 256 + q * 64 + 2 * lane];
    float f1 = h0[d * 256 + q * 64 + 2 * lane + 1];
    hq[q][lane] = (unsigned)f16b(f0) | ((unsigned)f16b(f1) << 16);
  }
  float c = 0.f;
  if (tid < 16) c = c0[d * 256 + sub * 16 + tid];

  const float* zp_d = zpre + (size_t)d * T * 1024;
  float* h_d = h_all + (size_t)d * T * 256;
  unsigned long long* rg = ring + (size_t)d * 2 * 128;

  // zpre for s=0, held by the 16 updater threads (4 gates each)
  float zv4[4] = {0.f, 0.f, 0.f, 0.f};
  if (tid < 16) {
    int t0 = d ? (T - 1) : 0;
#pragma unroll
    for (int g = 0; g < 4; g++)
      zv4[g] = zp_d[(size_t)t0 * 1024 + g * 256 + sub * 16 + tid];
  }
  __syncthreads();                                  // staging + h0 visible

  for (int s = 0; s < T; s++) {
    int t = d ? (T - 1 - s) : s;
    // prefetch next-step zpre BEFORE the poll: HBM latency hides under spin
    float zn4[4] = {0.f, 0.f, 0.f, 0.f};
    if (tid < 16 && s + 1 < T) {
      int tn = d ? (t - 1) : (t + 1);
#pragma unroll
      for (int g = 0; g < 4; g++)
        zn4[g] = zp_d[(size_t)tn * 1024 + g * 256 + sub * 16 + tid];
    }

    if (s > 0 && lane < 32) {
      unsigned long long v =
          poll2(&rg[((s - 1) & 1) * 128 + q * 32 + lane], (unsigned)s);
      hq[q][lane] = (unsigned)v;                    // wave-private slice
    }
    __builtin_amdgcn_wave_barrier();                // order hq write vs reads

    const uint4* hv = (const uint4*)hq[q];
    float acc = 0.f;
#pragma unroll
    for (int m = 0; m < 8; m++) {
      uint4 wv4 = wl4[(q * 8 + m) * 64 + lane];     // contiguous b128
      uint4 hv4 = hv[m];                            // wave-uniform broadcast
      acc = dot2acc(wv4.x, hv4.x, acc);
      acc = dot2acc(wv4.y, hv4.y, acc);
      acc = dot2acc(wv4.z, hv4.z, acc);
      acc = dot2acc(wv4.w, hv4.w, acc);
    }
    z_part[q][lane] = acc;
    lds_barrier();                                  // (1) partials ready

    if (tid < 16) {
      float a[4];
#pragma unroll
      for (int g = 0; g < 4; g++) {
        int r = g * 16 + tid;
        float z = z_part[0][r] + z_part[1][r] + z_part[2][r] + z_part[3][r]
                + zv4[g];
        a[g] = (g == 2) ? tanh_fast(z) : sigm_fast(z);
      }
      c = a[1] * c + a[0] * a[2];
      float hvl = a[3] * tanh_fast(c);
      h_d[(size_t)t * 256 + sub * 16 + tid] = hvl;  // fp32 history for k3
      float hn = __shfl_down(hvl, 1);
      if ((tid & 1) == 0) {                         // pack 2 h per tagged entry
        unsigned h2 = (unsigned)f16b(hvl) | ((unsigned)f16b(hn) << 16);
        __hip_atomic_store(&rg[(s & 1) * 128 + sub * 8 + (tid >> 1)],
                           ((unsigned long long)(unsigned)(s + 1) << 32) | h2,
                           __ATOMIC_RELAXED, __HIP_MEMORY_SCOPE_AGENT);
      }
#pragma unroll
      for (int g = 0; g < 4; g++) zv4[g] = zn4[g];
    }
    lds_barrier();                                  // (2) z_part safe to reuse
  }
}

// ---------------------------------------------------------------------------
// K3: feats[t][tag] = [hf[t]; hb[t]] . W_out[tag] + b_out[tag]
// ---------------------------------------------------------------------------
__global__ __launch_bounds__(64) void k3_feats(
    const float* __restrict__ h_all, const float* __restrict__ Wout,
    const float* __restrict__ bout, float* __restrict__ feats) {
  int t = blockIdx.x;
  int j = threadIdx.x;
  const float* hf = h_all + (size_t)t * 256;
  const float* hb = h_all + (size_t)T * 256 + (size_t)t * 256;
  float s[6];
#pragma unroll
  for (int g = 0; g < 6; g++) s[g] = 0.f;
#pragma unroll
  for (int m = 0; m < 4; m++) {
    float a = hf[j + 64 * m];
#pragma unroll
    for (int g = 0; g < 6; g++) s[g] += a * Wout[g * 512 + j + 64 * m];
  }
#pragma unroll
  for (int m = 0; m < 4; m++) {
    float b = hb[j + 64 * m];
#pragma unroll
    for (int g = 0; g < 6; g++) s[g] += b * Wout[g * 512 + 256 + j + 64 * m];
  }
#pragma unroll
  for (int g = 0; g < 6; g++) {
#pragma unroll
    for (int off = 32; off >= 1; off >>= 1) s[g] += __shfl_xor(s[g], off);
  }
  if (j < 6) feats[(size_t)t * 6 + j] = s[j] + bout[j];
}

// ---------------------------------------------------------------------------
// K4: Viterbi forward (serial, first-max argmax like jnp.argmax) + parallel
// backtrace via 6-entry map-composition suffix scan. Single wave.
// ---------------------------------------------------------------------------
__global__ __launch_bounds__(64) void k4_viterbi(
    const float* __restrict__ feats, const float* __restrict__ trans,
    float* __restrict__ out) {
  __shared__ unsigned char bp_lds[T * 8];
  __shared__ float fbuf[2][64 * 6];
  int lane = threadIdx.x;

  float tr[6];
#pragma unroll
  for (int f = 0; f < 6; f++) tr[f] = (lane < 6) ? trans[lane * 6 + f] : 0.f;
  float fv = (lane == START_TAG) ? 0.f : NEGV;

  for (int idx = lane; idx < 384; idx += 64) fbuf[0][idx] = feats[idx];

  for (int cch = 0; cch < 64; cch++) {
    float pf[6];
    if (cch + 1 < 64) {
#pragma unroll
      for (int m = 0; m < 6; m++)
        pf[m] = feats[(cch + 1) * 384 + lane + 64 * m];   // prefetch in regs
    }
    const float* fb = fbuf[cch & 1];
    for (int j = 0; j < 64; j++) {
      int t = cch * 64 + j;
      float best = -3.4e38f;
      int bi = 0;
#pragma unroll
      for (int f = 0; f < 6; f++) {
        float v = __shfl(fv, f) + tr[f];     // trans[to][from] + fv[from]
        if (v > best) { best = v; bi = f; }  // strict > => first max index
      }
      float nfv = best + fb[j * 6 + (lane < 6 ? lane : 0)];
      if (lane < 6) {
        fv = nfv;
        bp_lds[t * 8 + lane] = (unsigned char)bi;
      }
    }
    if (cch + 1 < 64) {
#pragma unroll
      for (int m = 0; m < 6; m++)
        fbuf[(cch + 1) & 1][lane + 64 * m] = pf[m];
    }
  }

  float term = (lane < 6) ? (fv + trans[STOP_TAG * 6 + lane]) : -3.4e38f;
  float bestv = -3.4e38f;
  int bestt = 0;
#pragma unroll
  for (int f = 0; f < 6; f++) {
    float v = __shfl(term, f);
    if (v > bestv) { bestv = v; bestt = f; }
  }
  if (lane == 0) out[0] = bestv;

  // backtrace: path[t] = S_t(best), S_t = M_{t+1} o ... o M_{T-1}
  unsigned int ident = 0;
#pragma unroll
  for (int i = 0; i < 6; i++) ident |= (unsigned)i << (3 * i);

  unsigned int p = ident;                 // P_L = M_{64L} o ... o M_{64L+63}
  int base = lane * 64;
  for (int j2 = 0; j2 < 64; j2++) {
    const unsigned int* bw = (const unsigned int*)&bp_lds[(base + j2) * 8];
    unsigned int lo = bw[0], hi = bw[1];
    unsigned int mw = (lo & 7) | (((lo >> 8) & 7) << 3) | (((lo >> 16) & 7) << 6)
                    | (((lo >> 24) & 7) << 9) | ((hi & 7) << 12)
                    | (((hi >> 8) & 7) << 15);
    unsigned int np = 0;
#pragma unroll
    for (int i = 0; i < 6; i++) {
      unsigned int b = (mw >> (3 * i)) & 7;
      np |= ((p >> (3 * b)) & 7) << (3 * i);   // p := p o M_t
    }
    p = np;
  }
  unsigned int suf = p;   // suffix scan: suf_L = P_L o ... o P_63
#pragma unroll
  for (int off = 1; off < 64; off <<= 1) {
    unsigned int other = __shfl_down(suf, off);
    if (lane + off < 64) {
      unsigned int ns = 0;
#pragma unroll
      for (int i = 0; i < 6; i++) {
        unsigned int b = (other >> (3 * i)) & 7;
        ns |= ((suf >> (3 * b)) & 7) << (3 * i);   // suf := suf o other
      }
      suf = ns;
    }
  }
  unsigned int tail = __shfl_down(suf, 1);     // Suf_{L+1}
  if (lane == 63) tail = ident;
  unsigned int cur = tail;                     // = S_{64L+63}
  for (int j2 = 63; j2 >= 0; j2--) {
    int t = base + j2;
    out[1 + t] = (float)((cur >> (3 * bestt)) & 7);
    const unsigned int* bw = (const unsigned int*)&bp_lds[t * 8];
    unsigned int lo = bw[0], hi = bw[1];
    unsigned int mw = (lo & 7) | (((lo >> 8) & 7) << 3) | (((lo >> 16) & 7) << 6)
                    | (((lo >> 24) & 7) << 9) | ((hi & 7) << 12)
                    | (((hi >> 8) & 7) << 15);
    unsigned int nc = 0;
#pragma unroll
    for (int i = 0; i < 6; i++) {
      unsigned int b = (cur >> (3 * i)) & 7;
      nc |= ((mw >> (3 * b)) & 7) << (3 * i);  // cur := M_t o cur
    }
    cur = nc;
  }
}

// ---------------------------------------------------------------------------
extern "C" void kernel_launch(void* const* d_in, const int* in_sizes, int n_in,
                              void* d_out, int out_size, void* d_ws, size_t ws_size,
                              hipStream_t stream) {
  const int*   sent  = (const int*)d_in[0];
  const float* emb   = (const float*)d_in[1];
  const float* wihf  = (const float*)d_in[2];
  const float* whhf  = (const float*)d_in[3];
  const float* bihf  = (const float*)d_in[4];
  const float* bhhf  = (const float*)d_in[5];
  const float* wihb  = (const float*)d_in[6];
  const float* whhb  = (const float*)d_in[7];
  const float* bihb  = (const float*)d_in[8];
  const float* bhhb  = (const float*)d_in[9];
  const float* Wout  = (const float*)d_in[10];
  const float* bout  = (const float*)d_in[11];
  const float* trans = (const float*)d_in[12];
  const float* h0    = (const float*)d_in[13];
  const float* c0    = (const float*)d_in[14];
  float* out = (float*)d_out;

  char* ws = (char*)d_ws;
  float*              zpre  = (float*)(ws + 0);          // 32 MiB
  float*              h_all = (float*)(ws + 33554432);   //  8 MiB
  float*              wT    = (float*)(ws + 41943040);   //  2 MiB
  float*              bias2 = (float*)(ws + 44040192);   //  8 KiB
  float*              feats = (float*)(ws + 44048384);   // 96 KiB
  unsigned long long* ring  = (unsigned long long*)(ws + 44146688); // 4 KiB

  k0_prep<<<2048, 256, 0, stream>>>(wihf, wihb, bihf, bhhf, bihb, bhhb, wT, bias2);
  dim3 g1(128, 8);
  k1_zpre<<<g1, 256, 0, stream>>>(sent, emb, wT, bias2, zpre);
  k2_lstm<<<32, 256, 0, stream>>>(zpre, whhf, whhb, h0, c0, h_all, ring);
  k3_feats<<<4096, 64, 0, stream>>>(h_all, Wout, bout, feats);
  k4_viterbi<<<1, 64, 0, stream>>>(feats, trans, out);
}